// Round 1
// 468.289 us; speedup vs baseline: 1.1856x; 1.1856x over previous
//
#include <hip/hip_runtime.h>
#include <stdint.h>

// Problem shape (fixed by the reference): M = B*S = 8192, K = DIN = 4096, N = DOUT = 4096
#define MDIM 8192
#define KDIM 4096
#define NDIM 4096
#define BK   64
#define NKT  (KDIM / BK)   // 64 K-tiles

typedef float f32x4 __attribute__((ext_vector_type(4)));
typedef __bf16 bf16x8 __attribute__((ext_vector_type(8)));
typedef short short8 __attribute__((ext_vector_type(8)));
typedef float fl4 __attribute__((ext_vector_type(4)));
typedef int i32x4 __attribute__((ext_vector_type(4)));

// fp32 -> bf16 bits, round-to-nearest-even (values here are small integers: exact <= 256)
__device__ __forceinline__ short f2bf_bits(float f) {
    unsigned int u = __float_as_uint(f);
    u += 0x7fffu + ((u >> 16) & 1u);
    return (short)(u >> 16);
}

// async global->LDS, 16B per lane; LDS dest is wave-uniform base + lane*16 (HW semantics)
__device__ __forceinline__ void gload_lds16(const void* g, void* l) {
    __builtin_amdgcn_global_load_lds(
        (__attribute__((address_space(1))) void*)(uintptr_t)g,
        (__attribute__((address_space(3))) void*)(uintptr_t)l,
        16, 0, 0);
}

// ---------------- quant kernels: grid-stride, 2048 blocks (G11) ----------------
__global__ void __launch_bounds__(256) quant_x_kernel(const float* __restrict__ x,
                                                      short* __restrict__ xq,
                                                      const float* __restrict__ p_is) {
    const float inv_is = 1.0f / p_is[0];
    const int64_t stride = (int64_t)gridDim.x * 256 * 8;
    for (int64_t i = ((int64_t)blockIdx.x * 256 + threadIdx.x) * 8;
         i < (int64_t)MDIM * KDIM; i += stride) {
        fl4 a = __builtin_nontemporal_load((const fl4*)(x + i));
        fl4 b = __builtin_nontemporal_load((const fl4*)(x + i + 4));
        short8 o;
        o[0] = f2bf_bits(rintf(a[0] * inv_is));
        o[1] = f2bf_bits(rintf(a[1] * inv_is));
        o[2] = f2bf_bits(rintf(a[2] * inv_is));
        o[3] = f2bf_bits(rintf(a[3] * inv_is));
        o[4] = f2bf_bits(rintf(b[0] * inv_is));
        o[5] = f2bf_bits(rintf(b[1] * inv_is));
        o[6] = f2bf_bits(rintf(b[2] * inv_is));
        o[7] = f2bf_bits(rintf(b[3] * inv_is));
        *(short8*)(xq + i) = o;   // normal store: gemm re-reads xq, let L3 keep it
    }
}

__global__ void __launch_bounds__(256) quant_w_kernel(const int* __restrict__ w,
                                                      short* __restrict__ wq) {
    const int64_t stride = (int64_t)gridDim.x * 256 * 8;
    for (int64_t i = ((int64_t)blockIdx.x * 256 + threadIdx.x) * 8;
         i < (int64_t)NDIM * KDIM; i += stride) {
        i32x4 a = __builtin_nontemporal_load((const i32x4*)(w + i));
        i32x4 b = __builtin_nontemporal_load((const i32x4*)(w + i + 4));
        short8 o;
        o[0] = f2bf_bits((float)a[0]);
        o[1] = f2bf_bits((float)a[1]);
        o[2] = f2bf_bits((float)a[2]);
        o[3] = f2bf_bits((float)a[3]);
        o[4] = f2bf_bits((float)b[0]);
        o[5] = f2bf_bits((float)b[1]);
        o[6] = f2bf_bits((float)b[2]);
        o[7] = f2bf_bits((float)b[3]);
        *(short8*)(wq + i) = o;
    }
}

// ---------------- GEMM: 256x256 tile, BK=64, 8 waves, 8-phase counted-vmcnt ----------------
// NT GEMM: C[m,n] = sum_k A[m,k]*B[n,k], fused int8-requant epilogue.
// R4: port of the 256^2 8-phase template (T2 swizzle + T3/T4 counted vmcnt + T5 setprio).
//   - waves 2(M)x4(N); per-wave output 128x64 = acc[8][4] f32x4.
//   - LDS 128 KiB: A[2][256][64] + B[2][256][64] bf16, double-buffered K-tiles.
//   - T2: LDS chunk (row,c) holds global chunk c^(row&7); linear global_load_lds dest,
//     inverse-swizzled per-lane GLOBAL source; ds_read XORs with r16&7 -> 2-way (free).
//   - stage schedule (1 half-tile = 2 x gload_lds16 per phase); region is written only
//     >=1 phase after its last ds_read (barrier-gated):
//       P0: buf1<-A.h0(t1)  P1: buf1<-A.h1(t1)   [buf1 A freed at prev P6]
//       P2: buf0<-B.h0(t0+2) P3: buf0<-B.h1(t0+2) [buf0 B freed at P1]
//       P4: buf0<-A.h0(t0+2) P5: buf0<-A.h1(t0+2) [buf0 A freed at P2]
//       P6: buf1<-B.h0(t1+2) P7: buf1<-B.h1(t1+2) [buf1 B freed at P5]
//     vmcnt(4) ONLY at P3-end (covers the 8 oldest = all of buf1/t1 before P4 reads it)
//     and P7-end (covers all of buf0/t0+2 before next P0). Never vmcnt(0) in the loop.

#define PH_MID() do { \
    __builtin_amdgcn_s_barrier(); \
    asm volatile("s_waitcnt lgkmcnt(0)" ::: "memory"); \
    __builtin_amdgcn_sched_barrier(0); \
    __builtin_amdgcn_s_setprio(1); \
  } while (0)

#define PH_END() do { \
    __builtin_amdgcn_s_setprio(0); \
    __builtin_amdgcn_s_barrier(); \
    __builtin_amdgcn_sched_barrier(0); \
  } while (0)

#define PH_END_VM() do { \
    __builtin_amdgcn_s_setprio(0); \
    asm volatile("s_waitcnt vmcnt(4)" ::: "memory"); \
    __builtin_amdgcn_s_barrier(); \
    __builtin_amdgcn_sched_barrier(0); \
  } while (0)

__global__ void __launch_bounds__(512, 2) gemm_bf16_kernel(
    const short* __restrict__ A,     // [MDIM][KDIM] bf16 bits
    const short* __restrict__ Bw,    // [NDIM][KDIM] bf16 bits
    const int* __restrict__ bias,    // [NDIM]
    const float* __restrict__ wscale,// [NDIM]
    const float* __restrict__ p_is,
    const float* __restrict__ p_os,
    int* __restrict__ out) {         // [MDIM][NDIM] int32
    // A bufs: lds[b*16384 + row*64 + ch*8]; B bufs: +32768. 65536 shorts = 128 KiB.
    __shared__ __align__(16) short lds[65536];

    const int tid  = threadIdx.x;
    const int lane = tid & 63;
    const int wave = tid >> 6;
    const int quad = lane >> 4;
    const int r16  = lane & 15;
    const int sw   = r16 & 7;

    const int n0 = blockIdx.x * 256;   // gridDim.x = 16
    const int m0 = blockIdx.y * 256;   // gridDim.y = 32

    const int wmi = wave >> 2;         // 0..1  M wave-row (128 rows each)
    const int wni = wave & 3;          // 0..3  N wave-col (64 cols each)

    // ---- staging (write side): chunk c = l*512 + tid; row=c>>3, kc=c&7;
    //      source column chunk = kc ^ (row&7)  (rows +64 keep row&7 -> per-thread const)
    const int srow = tid >> 3;                       // 0..63
    const int skc  = (tid & 7) ^ (srow & 7);
    const short* gA = A  + (int64_t)(m0 + srow) * KDIM + skc * 8;
    const short* gB = Bw + (int64_t)(n0 + srow) * KDIM + skc * 8;

#define STAGE_A(b, ha, T) do { \
    const short* _g = gA + (int64_t)((ha) * 128) * KDIM + (T) * BK; \
    gload_lds16(_g,             &lds[(b)*16384 + (ha)*8192 + wave*512]); \
    gload_lds16(_g + 64*KDIM,   &lds[(b)*16384 + (ha)*8192 + 4096 + wave*512]); \
  } while (0)
#define STAGE_B(b, ha, T) do { \
    const short* _g = gB + (int64_t)((ha) * 128) * KDIM + (T) * BK; \
    gload_lds16(_g,             &lds[32768 + (b)*16384 + (ha)*8192 + wave*512]); \
    gload_lds16(_g + 64*KDIM,   &lds[32768 + (b)*16384 + (ha)*8192 + 4096 + wave*512]); \
  } while (0)

    // ---- read side: row = <mult of 8> + r16, so row&7 == sw; chunk = (ks*4|quad)^sw
    const int aRowOff = (wmi * 128 + r16) * 64;          // + (mh*64 + mi*16)*64
    const int bRowOff = 32768 + (wni * 64 + r16) * 64;   // + (nh*32 + nj*16)*64
    const int cOff0   = (quad ^ sw) * 8;
    const int cOff1   = cOff0 ^ 32;                      // ks=1 flips chunk bit 2

#define LDA(b, mh, mi, ks) \
    (*(const bf16x8*)&lds[(b)*16384 + aRowOff + ((mh)*64 + (mi)*16)*64 + ((ks) ? cOff1 : cOff0)])
#define LDB(b, nh, nj, ks) \
    (*(const bf16x8*)&lds[(b)*16384 + bRowOff + ((nh)*32 + (nj)*16)*64 + ((ks) ? cOff1 : cOff0)])

#define READ_A(b, mh) do { \
    _Pragma("unroll") for (int mi = 0; mi < 4; ++mi) { \
        aR[mi][0] = LDA(b, mh, mi, 0); aR[mi][1] = LDA(b, mh, mi, 1); } \
  } while (0)
#define READ_B(b, nh, dst) do { \
    _Pragma("unroll") for (int nj = 0; nj < 2; ++nj) { \
        dst[nj][0] = LDB(b, nh, nj, 0); dst[nj][1] = LDB(b, nh, nj, 1); } \
  } while (0)
#define MFMA_Q(mh, nh, bsrc) do { \
    _Pragma("unroll") for (int mi = 0; mi < 4; ++mi) \
    _Pragma("unroll") for (int nj = 0; nj < 2; ++nj) \
    _Pragma("unroll") for (int ks = 0; ks < 2; ++ks) \
        acc[(mh)*4 + mi][(nh)*2 + nj] = __builtin_amdgcn_mfma_f32_16x16x32_bf16( \
            aR[mi][ks], bsrc[nj][ks], acc[(mh)*4 + mi][(nh)*2 + nj], 0, 0, 0); \
  } while (0)

    f32x4 acc[8][4];
#pragma unroll
    for (int i = 0; i < 8; ++i)
#pragma unroll
        for (int j = 0; j < 4; ++j) acc[i][j] = (f32x4)0.0f;

    bf16x8 aR[4][2], bLo[2][2], bHi[2][2];

    // ---- prologue: tile 0 -> buf0 (8 loads), tile 1 B-halves -> buf1 (4 loads) ----
    STAGE_A(0, 0, 0); STAGE_A(0, 1, 0);
    STAGE_B(0, 0, 0); STAGE_B(0, 1, 0);
    STAGE_B(1, 0, 1); STAGE_B(1, 1, 1);
    asm volatile("s_waitcnt vmcnt(4)" ::: "memory");   // tile 0 (oldest 8) landed
    __builtin_amdgcn_s_barrier();
    __builtin_amdgcn_sched_barrier(0);

    for (int it = 0; it < NKT / 2; ++it) {
        const int t1 = 2 * it + 1;
        const int tA = (2 * it + 2) & (NKT - 1);   // wraps harmlessly on last iter
        const int tB = (2 * it + 3) & (NKT - 1);

        // P0: compute buf0 q(mh0,nlo)
        READ_A(0, 0); READ_B(0, 0, bLo);
        STAGE_A(1, 0, t1);
        asm volatile("s_waitcnt lgkmcnt(8)" ::: "memory");  // 12 ds_reads issued this phase
        PH_MID(); MFMA_Q(0, 0, bLo); PH_END();
        // P1: q(mh0,nhi)
        READ_B(0, 1, bHi);
        STAGE_A(1, 1, t1);
        PH_MID(); MFMA_Q(0, 1, bHi); PH_END();
        // P2: q(mh1,nhi)
        READ_A(0, 1);
        STAGE_B(0, 0, tA);
        PH_MID(); MFMA_Q(1, 1, bHi); PH_END();
        // P3: q(mh1,nlo); counted wait -> buf1 (t1) fully landed for P4
        STAGE_B(0, 1, tA);
        PH_MID(); MFMA_Q(1, 0, bLo); PH_END_VM();
        // P4: compute buf1 q(mh0,nlo)
        READ_A(1, 0); READ_B(1, 0, bLo);
        STAGE_A(0, 0, tA);
        asm volatile("s_waitcnt lgkmcnt(8)" ::: "memory");
        PH_MID(); MFMA_Q(0, 0, bLo); PH_END();
        // P5: q(mh0,nhi)
        READ_B(1, 1, bHi);
        STAGE_A(0, 1, tA);
        PH_MID(); MFMA_Q(0, 1, bHi); PH_END();
        // P6: q(mh1,nhi)
        READ_A(1, 1);
        STAGE_B(1, 0, tB);
        PH_MID(); MFMA_Q(1, 1, bHi); PH_END();
        // P7: q(mh1,nlo); counted wait -> buf0 (tA) fully landed for next P0
        STAGE_B(1, 1, tB);
        PH_MID(); MFMA_Q(1, 0, bLo); PH_END_VM();
    }

    // ---- epilogue: out = round((is*ws[n]*acc + bias[n]) / os) ----
    const float is = p_is[0];
    const float inv_os = 1.0f / p_os[0];
    const int colBase = n0 + wni * 64;

    float alpha[4], beta[4];
#pragma unroll
    for (int nj = 0; nj < 4; ++nj) {
        const int col = colBase + nj * 16 + r16;
        alpha[nj] = is * wscale[col] * inv_os;
        beta[nj]  = (float)bias[col] * inv_os;
    }

    // C/D layout (verified m89/m91): col = lane&15, row = quad*4 + reg
#pragma unroll
    for (int mi = 0; mi < 8; ++mi) {
        const int row0 = m0 + wmi * 128 + mi * 16 + quad * 4;
#pragma unroll
        for (int nj = 0; nj < 4; ++nj) {
            const int col = colBase + nj * 16 + r16;
#pragma unroll
            for (int reg = 0; reg < 4; ++reg) {
                const float v = acc[mi][nj][reg] * alpha[nj] + beta[nj];
                __builtin_nontemporal_store(__float2int_rn(v),
                                            out + (int64_t)(row0 + reg) * NDIM + col);
            }
        }
    }
}

extern "C" void kernel_launch(void* const* d_in, const int* in_sizes, int n_in,
                              void* d_out, int out_size, void* d_ws, size_t ws_size,
                              hipStream_t stream) {
    (void)in_sizes; (void)n_in; (void)out_size; (void)ws_size;
    const float* x      = (const float*)d_in[0];
    const int*   weight = (const int*)d_in[1];
    const int*   bias   = (const int*)d_in[2];
    const float* wscale = (const float*)d_in[3];
    const float* p_is   = (const float*)d_in[4];
    const float* p_os   = (const float*)d_in[5];

    // workspace: xq bf16 [M,K] (64 MiB) + wq bf16 [N,K] (32 MiB) = 96 MiB
    short* xq = (short*)d_ws;
    short* wq = xq + (size_t)MDIM * KDIM;

    quant_x_kernel<<<2048, 256, 0, stream>>>(x, xq, p_is);
    quant_w_kernel<<<2048, 256, 0, stream>>>(weight, wq);

    dim3 grid(NDIM / 256, MDIM / 256);   // 16 x 32 = 512 blocks
    gemm_bf16_kernel<<<grid, 512, 0, stream>>>(xq, wq, bias, wscale, p_is, p_os, (int*)d_out);
}